// Round 3
// baseline (121.946 us; speedup 1.0000x reference)
//
#include <hip/hip_runtime.h>
#include <hip/hip_bf16.h>

// Problem dims (fixed by the reference setup_inputs)
#define BB 8
#define TT 4096
#define SS 256
#define DD 512

typedef __attribute__((ext_vector_type(8))) short short8;
typedef __attribute__((ext_vector_type(4))) float floatx4;
typedef __attribute__((ext_vector_type(4))) int intx4;

// Packed RNE f32x2 -> bf16x2 (v_cvt_pk_bf16_f32 on gfx950).
__device__ inline int pk2(float a, float b) {
  __hip_bfloat162 h = __float22bfloat162_rn(make_float2(a, b));
  int r;
  __builtin_memcpy(&r, &h, 4);
  return r;
}

// Pack 8 consecutive-k f32 values into a bf16 MFMA fragment.
__device__ inline short8 cvt8(float4 f0, float4 f1) {
  intx4 p;
  p[0] = pk2(f0.x, f0.y);
  p[1] = pk2(f0.z, f0.w);
  p[2] = pk2(f1.x, f1.y);
  p[3] = pk2(f1.z, f1.w);
  return __builtin_bit_cast(short8, p);
}

// K1 (UNCHANGED, verified): pack spk (8,256,512) f32 -> bf16 in
// MFMA-FRAGMENT order so K2 loads each B fragment as ONE coalesced
// global_load_dwordx4 per wave.
//   frag_idx = ((((b*2+tn)*2+wn)*8+kt)*2+ks)*4 + in   (512 shorts each)
//   lane l of frag: row = tn*128+wn*64+in*16+(l&15),
//                   k   = kt*64+ks*32+(l>>4)*8 .. +8
__global__ __launch_bounds__(256) void cos_packB_kernel(
    const float* __restrict__ spk, short* __restrict__ bp) {
  const int id = blockIdx.x;  // 512 blocks = (b, tn, wn, kt, ks)
  const int ks = id & 1;
  const int kt = (id >> 1) & 7;
  const int wn = (id >> 4) & 1;
  const int tn = (id >> 5) & 1;
  const int b = id >> 6;
  const int t = threadIdx.x;  // 256 = 4 in x 64 lane
  const int in = t >> 6;
  const int lane = t & 63;
  const int row = tn * 128 + wn * 64 + in * 16 + (lane & 15);
  const int k = kt * 64 + ks * 32 + (lane >> 4) * 8;
  const float* src = spk + ((size_t)(b * SS + row)) * DD + k;
  float4 f0 = *(const float4*)src;
  float4 f1 = *(const float4*)(src + 4);
  short8 o = cvt8(f0, f1);
  size_t frag = (size_t)((((b * 2 + tn) * 2 + wn) * 8 + kt) * 2 + ks) * 4 + in;
  *(short8*)(bp + frag * 512 + (size_t)lane * 8) = o;
}

// K2: fused cosine scorer. ROUND-3 CHANGE vs verified round-1: SAME
// 128x128 tile, SAME 64 KB double-buffered A staging (identical 2048-unit
// XOR-16 swizzle map), SAME grid/XCD swizzle and barrier structure — but
// 512 threads / 8 waves per block (2x4 wave grid, per-wave 64x32 output).
// 2 blocks/CU x 8 waves = 16 waves/CU = 4 waves/SIMD (was 2) for latency
// hiding of the A-DMA + B register loads. __launch_bounds__(512,4) caps
// VGPR at 128 (est ~110 live).
__global__ __launch_bounds__(512, 4) void cos_fused_kernel(
    const float* __restrict__ xs, const short* __restrict__ bp,
    float* __restrict__ out) {
  __shared__ float sA[2 * 128 * 64];  // 64 KB: double-buffered A tile
  float* scX = sA;                    // aliased: only used after the k-loop
  float* scY = sA + 128;

  const int tid = threadIdx.x;
  const int wave = tid >> 6;  // 0..7
  const int lane = tid & 63;

  // XCD swizzle (identical to verified round-1; bijective over 512 blocks):
  // XCD x owns batch b == x; tn-pairs of one (b,tm) A panel adjacent.
  const int id = blockIdx.x;
  const int xcd = id & 7;
  const int j = id >> 3;                    // 0..63
  const int pairIdx = xcd * 32 + (j >> 1);  // 0..255
  const int tn = j & 1;
  const int tm = pairIdx & 31;  // 128-row panel index, 0..31
  const int b = pairIdx >> 5;   // == xcd

  const int wm = wave >> 2;   // 0..1: 64-row half
  const int wn = wave & 3;    // 0..3: 32-col quarter
  const int quad = lane >> 4;
  const int l15 = lane & 15;
  // Gram roles: (0,0),(1,1) -> A-grams; (1,0),(0,1),(0,2),(0,3) -> B-grams
  // (cols wn*32..+31 each, all 128 covered once); (1,2),(1,3) -> none.
  const int role = (wn == wm) ? 1 : ((wm == ((wn == 0) ? 1 : 0)) ? 2 : 0);

  const float* Abase = xs + ((size_t)b * TT + tm * 128) * DD;
  // B fragment base: K1 granule key (b, tn, wnK1 = wn>>1); 16-col tile
  // within granule inK1 = (wn&1)*2 + in.
  const short* Bw =
      bp + (size_t)((b * 2 + tn) * 2 + (wn >> 1)) * 32768 + (size_t)lane * 8;
  const int inbase = (wn & 1) * 2;  // inK1 = inbase + in

  floatx4 acc[4][2];
#pragma unroll
  for (int i = 0; i < 4; i++)
#pragma unroll
    for (int jj = 0; jj < 2; jj++) acc[i][jj] = (floatx4){0.f, 0.f, 0.f, 0.f};
  floatx4 accG[4];  // gram accumulators (A: 4 row-tiles; B: 2 col-tiles)
#pragma unroll
  for (int i = 0; i < 4; i++) accG[i] = (floatx4){0.f, 0.f, 0.f, 0.f};

  // A staging map (identical swizzle to round-1, redistributed over 512
  // threads): 16B unit s = jj*512 + tid; row = s>>4 (16 units/row); slot
  // s&15 holds logical k-block (s&15) ^ (row&15)  [XOR-16 swizzle].
  int aoff[4];
#pragma unroll
  for (int jj = 0; jj < 4; jj++) {
    int s = jj * 512 + tid;
    int row = s >> 4;
    int blk = (s & 15) ^ (row & 15);
    aoff[jj] = row * DD + blk * 4;
  }

  // Prologue: stage kt=0 into buffer 0, full drain once.
#pragma unroll
  for (int jj = 0; jj < 4; jj++) {
    __builtin_amdgcn_global_load_lds(
        (const __attribute__((address_space(1))) unsigned int*)(Abase +
            aoff[jj]),
        (__attribute__((address_space(3))) unsigned int*)(sA +
            (jj * 512 + wave * 64) * 4),
        16, 0, 0);
  }
  __syncthreads();

  for (int kt = 0; kt < 8; ++kt) {
    const int cur = kt & 1;

    // B fragments for this kt -> registers (4 x 16B coalesced per wave).
    // Issued FIRST so their vmcnt wait (oldest-first) completes without
    // draining the A DMA below.
    short8 breg[2][2];
    const short* Bkt = Bw + kt * 4096;
#pragma unroll
    for (int ksl = 0; ksl < 2; ksl++)
#pragma unroll
      for (int in = 0; in < 2; in++)
        breg[ksl][in] =
            *(const short8*)(Bkt + ksl * 2048 + (inbase + in) * 512);

    // Stage kt+1 into the other buffer; overlaps this kt's compute, drained
    // at the single syncthreads at the bottom.
    if (kt < 7) {
#pragma unroll
      for (int jj = 0; jj < 4; jj++) {
        __builtin_amdgcn_global_load_lds(
            (const __attribute__((address_space(1))) unsigned int*)(Abase +
                aoff[jj] + (kt + 1) * 64),
            (__attribute__((address_space(3))) unsigned int*)(sA +
                (cur ^ 1) * 8192 + (jj * 512 + wave * 64) * 4),
            16, 0, 0);
      }
    }

    const float* sAc = sA + cur * 8192;
#pragma unroll
    for (int ks = 0; ks < 2; ks++) {
      short8 af[4];
      const int b0s = ks * 8 + quad * 2;  // first 16B f32 block of A frag
#pragma unroll
      for (int im = 0; im < 4; im++) {
        int row = wm * 64 + im * 16 + l15;
        int s0 = b0s ^ (row & 15);
        int s1 = (b0s + 1) ^ (row & 15);
        float4 f0 = *(const float4*)(sAc + row * 64 + s0 * 4);
        float4 f1 = *(const float4*)(sAc + row * 64 + s1 * 4);
        af[im] = cvt8(f0, f1);
      }
#pragma unroll
      for (int im = 0; im < 4; im++)
#pragma unroll
        for (int in = 0; in < 2; in++)
          acc[im][in] = __builtin_amdgcn_mfma_f32_16x16x32_bf16(
              af[im], breg[ks][in], acc[im][in], 0, 0, 0);
      if (role == 1) {
#pragma unroll
        for (int im = 0; im < 4; im++)
          accG[im] = __builtin_amdgcn_mfma_f32_16x16x32_bf16(
              af[im], af[im], accG[im], 0, 0, 0);
      } else if (role == 2) {
#pragma unroll
        for (int in = 0; in < 2; in++)
          accG[in] = __builtin_amdgcn_mfma_f32_16x16x32_bf16(
              breg[ks][in], breg[ks][in], accG[in], 0, 0, 0);
      }
    }
    __syncthreads();  // single barrier per kt: syncs reads + drains DMA
  }

  // Extract gram diagonals -> inverse norms. C/D layout: col = l15,
  // row = quad*4 + r; diagonal element d: lane l15==d, quad==d>>2, r=d&3.
  // scX/scY alias sA buffer 0: all reads done before the loop's last
  // barrier (kt=7 computes from buffer 1).
  if (quad == (l15 >> 2)) {
    if (role == 1) {
#pragma unroll
      for (int i = 0; i < 4; i++) {
        float inv = 1.0f / fmaxf(sqrtf(accG[i][l15 & 3]), 1e-8f);
        scX[wm * 64 + i * 16 + l15] = inv;  // rows 0..63 / 64..127
      }
    } else if (role == 2) {
#pragma unroll
      for (int i = 0; i < 2; i++) {
        float inv = 1.0f / fmaxf(sqrtf(accG[i][l15 & 3]), 1e-8f);
        scY[wn * 32 + i * 16 + l15] = inv;  // cols wn*32 .. +31
      }
    }
  }
  __syncthreads();

  // Epilogue: apply cosine scales (dot * (1/||x||) * (1/||y||)).
  float* Obase = out + ((size_t)b * TT + tm * 128) * SS + tn * 128;
#pragma unroll
  for (int im = 0; im < 4; im++) {
#pragma unroll
    for (int in = 0; in < 2; in++) {
      int col = wn * 32 + in * 16 + l15;
      float yv = scY[col];
#pragma unroll
      for (int r = 0; r < 4; r++) {
        int row = wm * 64 + im * 16 + quad * 4 + r;
        Obase[row * SS + col] = acc[im][in][r] * scX[row] * yv;
      }
    }
  }
}

extern "C" void kernel_launch(void* const* d_in, const int* in_sizes, int n_in,
                              void* d_out, int out_size, void* d_ws,
                              size_t ws_size, hipStream_t stream) {
  const float* xs = (const float*)d_in[0];   // (8,4096,512) f32
  const float* spk = (const float*)d_in[1];  // (8,256,512) f32
  float* out = (float*)d_out;                // (8,4096,256) f32
  short* bp = (short*)d_ws;                  // 2 MB packed bf16 B (frag order)

  hipLaunchKernelGGL(cos_packB_kernel, dim3(512), dim3(256), 0, stream, spk,
                     bp);
  hipLaunchKernelGGL(cos_fused_kernel, dim3(512), dim3(512), 0, stream, xs,
                     bp, out);
}

// Round 4
// 120.140 us; speedup vs baseline: 1.0150x; 1.0150x over previous
//
#include <hip/hip_runtime.h>
#include <hip/hip_bf16.h>

// Problem dims (fixed by the reference setup_inputs)
#define BB 8
#define TT 4096
#define SS 256
#define DD 512

typedef __attribute__((ext_vector_type(8))) short short8;
typedef __attribute__((ext_vector_type(4))) float floatx4;
typedef __attribute__((ext_vector_type(4))) int intx4;

// Packed RNE f32x2 -> bf16x2 (v_cvt_pk_bf16_f32 on gfx950).
__device__ inline int pk2(float a, float b) {
  __hip_bfloat162 h = __float22bfloat162_rn(make_float2(a, b));
  int r;
  __builtin_memcpy(&r, &h, 4);
  return r;
}

// Pack 8 consecutive-k f32 values into a bf16 MFMA fragment.
__device__ inline short8 cvt8(float4 f0, float4 f1) {
  intx4 p;
  p[0] = pk2(f0.x, f0.y);
  p[1] = pk2(f0.z, f0.w);
  p[2] = pk2(f1.x, f1.y);
  p[3] = pk2(f1.z, f1.w);
  return __builtin_bit_cast(short8, p);
}

// K1 (UNCHANGED, verified): pack spk (8,256,512) f32 -> bf16 in
// MFMA-FRAGMENT order so K2 loads each B fragment as ONE coalesced
// global_load_dwordx4 per wave.
//   frag_idx = ((((b*2+tn)*2+wn)*8+kt1)*2+ks1)*4 + in   (512 shorts each)
//   lane l of frag: row = tn*128+wn*64+in*16+(l&15),
//                   k   = kt1*64+ks1*32+(l>>4)*8 .. +8
__global__ __launch_bounds__(256) void cos_packB_kernel(
    const float* __restrict__ spk, short* __restrict__ bp) {
  const int id = blockIdx.x;  // 512 blocks = (b, tn, wn, kt, ks)
  const int ks = id & 1;
  const int kt = (id >> 1) & 7;
  const int wn = (id >> 4) & 1;
  const int tn = (id >> 5) & 1;
  const int b = id >> 6;
  const int t = threadIdx.x;  // 256 = 4 in x 64 lane
  const int in = t >> 6;
  const int lane = t & 63;
  const int row = tn * 128 + wn * 64 + in * 16 + (lane & 15);
  const int k = kt * 64 + ks * 32 + (lane >> 4) * 8;
  const float* src = spk + ((size_t)(b * SS + row)) * DD + k;
  float4 f0 = *(const float4*)src;
  float4 f1 = *(const float4*)(src + 4);
  short8 o = cvt8(f0, f1);
  size_t frag = (size_t)((((b * 2 + tn) * 2 + wn) * 8 + kt) * 2 + ks) * 4 + in;
  *(short8*)(bp + frag * 512 + (size_t)lane * 8) = o;
}

// K2: fused cosine scorer. ROUND-4 CHANGE vs verified R1: same 128x128
// tile / 4 waves / per-wave 64x64 / same K1 layout, grid, XCD swizzle,
// gram + epilogue math, bit-identical accumulation order — but the K-loop
// is now a COUNTED-VMCNT pipeline (T3+T4): BK=32, FOUR 16 KB LDS buffers
// (same 64 KB total), A-stage issued 3 iterations ahead, and each
// iteration ends with s_waitcnt vmcnt(16/12/8) + raw s_barrier — vmcnt
// never drains to 0 in the main loop (the old __syncthreads forced
// vmcnt(0) every kt, exposing the full cold-HBM latency of the stage).
// Buffer-reuse safety: barrier-per-iter keeps all waves in the same iter;
// stage(kt+3) writes buf[(kt+3)&3], readers at kt read buf[kt&3] — the
// written buffer's last readers finished before the barrier the writer
// already passed. vmcnt counts are tail-position-invariant under intra-
// iteration reordering (per-iter VMEM totals are fixed: 4 B-loads + 4
// stage-loads).
__global__ __launch_bounds__(256, 2) void cos_fused_kernel(
    const float* __restrict__ xs, const short* __restrict__ bp,
    float* __restrict__ out) {
  __shared__ float sA[4 * 128 * 32];  // 64 KB: quad-buffered A tile (BK=32)
  float* scX = sA;                    // aliased: only used after the k-loop
  float* scY = sA + 128;

  const int tid = threadIdx.x;
  const int wave = tid >> 6;
  const int lane = tid & 63;

  // XCD swizzle (identical to verified R1; bijective over 512 blocks):
  // XCD x owns batch b == x; tn-pairs of one (b,tm) A panel adjacent.
  const int id = blockIdx.x;
  const int xcd = id & 7;
  const int j = id >> 3;                    // 0..63
  const int pairIdx = xcd * 32 + (j >> 1);  // 0..255
  const int tn = j & 1;
  const int tm = pairIdx & 31;  // 128-row panel index, 0..31
  const int b = pairIdx >> 5;   // == xcd

  const int wm = wave >> 1;
  const int wn = wave & 1;
  const int quad = lane >> 4;
  const int l15 = lane & 15;
  const bool gramA = (wm == wn);

  const float* Abase = xs + ((size_t)b * TT + tm * 128) * DD;
  // Per-wave, per-lane B fragment base (shorts). K1 layout unchanged.
  const short* Bw =
      bp + (size_t)((b * 2 + tn) * 2 + wn) * 32768 + (size_t)lane * 8;

  floatx4 acc[4][4];
#pragma unroll
  for (int i = 0; i < 4; i++)
#pragma unroll
    for (int jj = 0; jj < 4; jj++) acc[i][jj] = (floatx4){0.f, 0.f, 0.f, 0.f};
  floatx4 accG[4];  // gram accumulators (A-rows if wm==wn else B-rows)
#pragma unroll
  for (int i = 0; i < 4; i++) accG[i] = (floatx4){0.f, 0.f, 0.f, 0.f};

  // A staging map for BK=32: per kt, 1024 16B units; unit s = jj*256 + tid;
  // row = s>>3 (8 units/row); stored slot s&7 holds logical k-block
  // (s&7) ^ (row&7)  [XOR-8 swizzle; 128 B LDS rows; fragment-read bank
  // check: 8 lanes/slot over 4 banks = 2-way = free].
  int aoff[4];
#pragma unroll
  for (int jj = 0; jj < 4; jj++) {
    int s = jj * 256 + tid;
    int row = s >> 3;
    int blk = (s & 7) ^ (row & 7);
    aoff[jj] = row * DD + blk * 4;
  }

// Issue one kt's A stage (16 KB) into buf[KT&3]. KT is compile-time under
// full unroll; LDS dest is linear per wave (wave-uniform base + lane*16).
#define STAGE(KT)                                                           \
  do {                                                                      \
    _Pragma("unroll") for (int jj = 0; jj < 4; jj++) {                      \
      __builtin_amdgcn_global_load_lds(                                     \
          (const __attribute__((address_space(1))) unsigned int*)(Abase +   \
              aoff[jj] + (KT) * 32),                                        \
          (__attribute__((address_space(3))) unsigned int*)(sA +            \
              ((KT) & 3) * 4096 + (jj * 256 + wave * 64) * 4),              \
          16, 0, 0);                                                        \
    }                                                                       \
  } while (0)

  short8 breg[2][4];  // statically indexed after full unroll (rule #20)

  // ---- Prologue: B(0) + stage(0) ... then stages 1,2; wait only stage(0).
#pragma unroll
  for (int in = 0; in < 4; in++)
    breg[0][in] = *(const short8*)(Bw + in * 512);
  STAGE(0);
  __builtin_amdgcn_sched_barrier(0);  // pin: stages 1,2 stay after stage(0)
  STAGE(1);
  STAGE(2);
  // stage(0) has >=8 ops after it -> vmcnt(8) guarantees it completed.
  asm volatile("s_waitcnt vmcnt(8)" ::: "memory");
  __builtin_amdgcn_sched_barrier(0);
  __builtin_amdgcn_s_barrier();
  __builtin_amdgcn_sched_barrier(0);

#pragma unroll
  for (int kt = 0; kt < 16; ++kt) {
    // B prefetch for kt+1 (consumed next iter; L2-resident, 1-deep is ample).
    if (kt + 1 < 16) {
      const short* Bn = Bw + ((kt + 1) >> 1) * 4096 + ((kt + 1) & 1) * 2048;
#pragma unroll
      for (int in = 0; in < 4; in++)
        breg[(kt + 1) & 1][in] = *(const short8*)(Bn + in * 512);
    }
    // A stage 3 deep.
    if (kt + 3 < 16) STAGE(kt + 3);

    // Compute kt from buf[kt&3]; stage(kt) completion was guaranteed by the
    // previous iteration's counted vmcnt + barrier.
    const float* sAc = sA + (kt & 3) * 4096;
    short8 af[4];
#pragma unroll
    for (int im = 0; im < 4; im++) {
      int row = wm * 64 + im * 16 + l15;
      int r7 = l15 & 7;  // row&7 == l15&7 (wm*64, im*16 are multiples of 8)
      int s0 = (quad * 2) ^ r7;
      int s1 = (quad * 2 + 1) ^ r7;
      float4 f0 = *(const float4*)(sAc + row * 32 + s0 * 4);
      float4 f1 = *(const float4*)(sAc + row * 32 + s1 * 4);
      af[im] = cvt8(f0, f1);
    }
#pragma unroll
    for (int im = 0; im < 4; im++)
#pragma unroll
      for (int in = 0; in < 4; in++)
        acc[im][in] = __builtin_amdgcn_mfma_f32_16x16x32_bf16(
            af[im], breg[kt & 1][in], acc[im][in], 0, 0, 0);
    if (gramA) {
#pragma unroll
      for (int im = 0; im < 4; im++)
        accG[im] = __builtin_amdgcn_mfma_f32_16x16x32_bf16(
            af[im], af[im], accG[im], 0, 0, 0);
    } else {
#pragma unroll
      for (int in = 0; in < 4; in++)
        accG[in] = __builtin_amdgcn_mfma_f32_16x16x32_bf16(
            breg[kt & 1][in], breg[kt & 1][in], accG[in], 0, 0, 0);
    }

    // End-of-iter: wait for stage(kt+1) WITHOUT draining deeper prefetch.
    // N = #VMEM ops issued after stage(kt+1) (tail-count, reorder-safe):
    //   kt==0: 12 (stage2 + B1 + stage3); kt 1..12: 16 (B,stage x2 iters);
    //   kt==13: 12 (B13+stage15+B14); kt==14: 8 (B14+B15); kt==15: none.
    if (kt < 15) {
      if (kt == 0)
        asm volatile("s_waitcnt vmcnt(12)" ::: "memory");
      else if (kt <= 12)
        asm volatile("s_waitcnt vmcnt(16)" ::: "memory");
      else if (kt == 13)
        asm volatile("s_waitcnt vmcnt(12)" ::: "memory");
      else
        asm volatile("s_waitcnt vmcnt(8)" ::: "memory");
      __builtin_amdgcn_sched_barrier(0);
      __builtin_amdgcn_s_barrier();
      __builtin_amdgcn_sched_barrier(0);
    }
  }
#undef STAGE
  __syncthreads();  // full drain once, before aliased scX/scY writes

  // Extract gram diagonals -> inverse norms. C/D layout: col = l15,
  // row = quad*4 + r; diagonal element d: lane l15==d, quad==d>>2, r=d&3.
  if (quad == (l15 >> 2)) {
#pragma unroll
    for (int i = 0; i < 4; i++) {
      float inv = 1.0f / fmaxf(sqrtf(accG[i][l15 & 3]), 1e-8f);
      if (gramA)
        scX[wm * 64 + i * 16 + l15] = inv;  // waves (0,0),(1,1): rows 0..127
      else
        scY[wn * 64 + i * 16 + l15] = inv;  // waves (0,1),(1,0): cols 0..127
    }
  }
  __syncthreads();

  // Epilogue: apply cosine scales (dot * (1/||x||) * (1/||y||)).
  float* Obase = out + ((size_t)b * TT + tm * 128) * SS + tn * 128;
#pragma unroll
  for (int im = 0; im < 4; im++) {
#pragma unroll
    for (int in = 0; in < 4; in++) {
      int col = wn * 64 + in * 16 + l15;
      float yv = scY[col];
#pragma unroll
      for (int r = 0; r < 4; r++) {
        int row = wm * 64 + im * 16 + quad * 4 + r;
        Obase[row * SS + col] = acc[im][in][r] * scX[row] * yv;
      }
    }
  }
}

extern "C" void kernel_launch(void* const* d_in, const int* in_sizes, int n_in,
                              void* d_out, int out_size, void* d_ws,
                              size_t ws_size, hipStream_t stream) {
  const float* xs = (const float*)d_in[0];   // (8,4096,512) f32
  const float* spk = (const float*)d_in[1];  // (8,256,512) f32
  float* out = (float*)d_out;                // (8,4096,256) f32
  short* bp = (short*)d_ws;                  // 2 MB packed bf16 B (frag order)

  hipLaunchKernelGGL(cos_packB_kernel, dim3(512), dim3(256), 0, stream, spk,
                     bp);
  hipLaunchKernelGGL(cos_fused_kernel, dim3(512), dim3(256), 0, stream, xs,
                     bp, out);
}